// Round 24
// baseline (227.278 us; speedup 1.0000x reference)
//
#include <hip/hip_runtime.h>
#include <hip/hip_bf16.h>

typedef __attribute__((ext_vector_type(8))) short short8;
typedef __attribute__((ext_vector_type(4))) short short4v;
typedef __attribute__((ext_vector_type(4))) float floatx4;

#define MFMA16x32(a,b,c) __builtin_amdgcn_mfma_f32_16x16x32_bf16((a),(b),(c),0,0,0)

// exact round-to-nearest-even bf16 (no NaN path -- all values bounded here)
static __device__ __forceinline__ unsigned short f2b(float f) {
  unsigned u = __builtin_bit_cast(unsigned, f);
  return (unsigned short)((u + 0x7fffu + ((u >> 16) & 1u)) >> 16);
}
static __device__ __forceinline__ float b2f(unsigned short u) {
  unsigned v = ((unsigned)u) << 16;
  return __builtin_bit_cast(float, v);
}

#define HH 192
#define WWID 192
#define HW (192*192)

// ---- ws layout (bytes) ----
#define YX_OFF   0                      // x NHWC bf16 -> overwritten in-place with y
#define H1_OFF   56623104               // h1 NHWC bf16 (fused conv1 out of k_attn)
#define AB_OFF   113246208              // attn_bias f32 PERMUTED [t][row*4+n], ×log2e
#define QKVW_OFF 113262592              // qkv_w bf16 192*96
#define OUTW_OFF 113299456              // out_w bf16 96*64
#define W1_OFF   113311744              // conv1_w bf16 96*96
#define W2R_OFF  113330176              // conv2_w reordered bf16 96*864

#define LOG2E 1.44269504088896f

// =====================================================================
// prep: attn bias projection (permuted, pre-scaled by log2e) + repacks
// =====================================================================
__global__ __launch_bounds__(256) void k_prep(
    const float* __restrict__ bias, const float* __restrict__ bpw,
    const float* __restrict__ qkv_w, const float* __restrict__ out_w,
    const float* __restrict__ w1, const float* __restrict__ w2,
    char* __restrict__ ws) {
  int tid = blockIdx.x * blockDim.x + threadIdx.x;
  int nth = gridDim.x * blockDim.x;
  float* ab = (float*)(ws + AB_OFF);
  unsigned short* qkvw = (unsigned short*)(ws + QKVW_OFF);
  unsigned short* outw = (unsigned short*)(ws + OUTW_OFF);
  unsigned short* w1b  = (unsigned short*)(ws + W1_OFF);
  unsigned short* w2r  = (unsigned short*)(ws + W2R_OFF);

  for (int i = tid; i < 4096; i += nth) {
    float s = 0.f;
    #pragma unroll 8
    for (int k = 0; k < 64; k++) s += bias[k] * bpw[i*64 + k];
    int c = i & 63;                       // col = n*16 + row
    ab[(i & ~63) + ((c & 15) << 2) + (c >> 4)] = s * LOG2E;  // [t][row*4+n]
  }
  for (int i = tid; i < 192*96; i += nth) qkvw[i] = f2b(qkv_w[i]);
  for (int i = tid; i < 96*64;  i += nth) outw[i] = f2b(out_w[i]);
  for (int i = tid; i < 96*96;  i += nth) w1b[i]  = f2b(w1[i]);
  for (int i = tid; i < 96*864; i += nth) {
    int o = i / 864, k = i % 864;
    int tap = k / 96, c = k % 96;
    w2r[i] = f2b(w2[(o*96 + c)*9 + tap]);   // (O,C,3,3) -> [o][tap*96+c]
  }
}

// =====================================================================
// layout transform: x NCHW fp32 -> yx NHWC bf16, coalesced both sides
// =====================================================================
__global__ __launch_bounds__(256) void k_xt(
    const float* __restrict__ x, unsigned short* __restrict__ xt) {
  __shared__ __align__(16) float tile[96*65];
  int blk = blockIdx.x;
  int b = blk / 576, rem = blk % 576;
  int i = rem / 3, j0 = (rem % 3) * 64;
  int tid = threadIdx.x;
  const float* xb = x + (size_t)b*96*HW + (size_t)i*WWID + j0;

  for (int f = tid; f < 1536; f += 256) {
    int c = f >> 4, q = f & 15;
    *(floatx4*)&tile[c*65 + 4*q] = *(const floatx4*)&xb[(size_t)c*HW + 4*q];
  }
  __syncthreads();
  unsigned short* xtb = xt + ((size_t)b*HW + (size_t)i*WWID + j0) * 96;
  for (int f = tid; f < 768; f += 256) {
    int p = f / 12, c0 = (f % 12) * 8;
    short8 o;
    #pragma unroll
    for (int u = 0; u < 8; u++) o[u] = (short)f2b(tile[(c0+u)*65 + p]);
    *(short8*)&xtb[p*96 + c0] = o;
  }
}

// =====================================================================
// window attention + residual + FUSED conv1: 1 block per 8x8 window,
// 4 waves (wave = head). R14-best layout, no setprio (A/B confirmed).
// LDS 33792B -> 4 blocks/CU. 2 barriers. Scalar phase5/6 epilogues.
// =====================================================================
__global__ __launch_bounds__(256,4) void k_attn(
    unsigned short* yx, const float* __restrict__ qkv_b,
    const float* __restrict__ out_b, const float* __restrict__ b1,
    const char* __restrict__ wsr, unsigned short* __restrict__ h1) {
  __shared__ __align__(16) char smem[33792];
  unsigned short* vt   = (unsigned short*)smem;
  unsigned short* qkw  = (unsigned short*)(smem + 9216);
  unsigned short* o64  = (unsigned short*)smem;          // alias vt after B1
  unsigned short* ybuf = (unsigned short*)(smem + 9216); // [64][104] after PV (pch dead)

  const float* ab = (const float*)(wsr + AB_OFF);
  const unsigned short* qkvw = (const unsigned short*)(wsr + QKVW_OFF);
  const unsigned short* outw = (const unsigned short*)(wsr + OUTW_OFF);
  const unsigned short* w1b  = (const unsigned short*)(wsr + W1_OFF);

  int blk = blockIdx.x;
  int b = blk / 576, rem = blk % 576;
  int wi = rem / 24, wj = rem % 24;
  int h0 = wi * 8, w0 = wj * 8;
  unsigned short* xtw = yx + (size_t)b*HW*96;   // read x, write y in-place
  unsigned short* h1w = h1 + (size_t)b*HW*96;

  int tid = threadIdx.x;
  int h = tid >> 6, ln = tid & 63;
  int row = ln & 15, kg = ln >> 4;

  unsigned short* qh = qkw + h*3072;    // [64][24] u16
  unsigned short* kh = qh + 1536;       // [64][24] u16
  unsigned short* pch = qh;             // pchunk [64][40] aliases q+k (wave-local)

  const floatx4 zf = {0.f, 0.f, 0.f, 0.f};
  const short8 zs = {0,0,0,0,0,0,0,0};
  const short one_b = (short)0x3F80;    // bf16 1.0
  const short8 one8 = {one_b,one_b,one_b,one_b,one_b,one_b,one_b,one_b};

  // ---- phase 2: qkv GEMM, A straight from global yx; wave h owns head h ----
  floatx4 accq[4][3];
  #pragma unroll
  for (int m = 0; m < 4; m++)
    #pragma unroll
    for (int n = 0; n < 3; n++) accq[m][n] = zf;
  #pragma unroll
  for (int ks = 0; ks < 3; ks++) {
    int c0 = ks*32 + kg*8;
    short8 a[4], bb[3];
    #pragma unroll
    for (int m = 0; m < 4; m++) {
      int t = m*16 + row;
      a[m] = *(const short8*)&xtw[((size_t)((h0 + (t>>3))*WWID + w0 + (t&7)))*96 + c0];
    }
    #pragma unroll
    for (int n = 0; n < 3; n++)   // jt = n*4 + h  (q_h, k_h, v_h)
      bb[n] = *(const short8*)&qkvw[((n*4 + h)*16 + row)*96 + c0];
    #pragma unroll
    for (int m = 0; m < 4; m++)
      #pragma unroll
      for (int n = 0; n < 3; n++) accq[m][n] = MFMA16x32(a[m], bb[n], accq[m][n]);
  }
  float qb0 = qkv_b[h*16 + row], qb1 = qkv_b[64 + h*16 + row], qb2 = qkv_b[128 + h*16 + row];
  #pragma unroll
  for (int m = 0; m < 4; m++) {
    #pragma unroll
    for (int r = 0; r < 4; r++) {
      int t = m*16 + kg*4 + r;
      qh[t*24 + row] = f2b(accq[m][0][r] + qb0);
      kh[t*24 + row] = f2b(accq[m][1][r] + qb1);
    }
    short4v vv;
    #pragma unroll
    for (int r = 0; r < 4; r++) vv[r] = (short)f2b(accq[m][2][r] + qb2);
    *(short4v*)&vt[(h*16 + row)*72 + m*16 + kg*4] = vv;   // vt[d][t] packed b64
  }
  asm volatile("" ::: "memory");

  // ---- phase 3: scores (K=16 zero-padded) + exp (no max; denom via MFMA) ----
  short8 kb[4];
  #pragma unroll
  for (int n = 0; n < 4; n++)
    kb[n] = (kg < 2) ? *(const short8*)&kh[(n*16 + row)*24 + kg*8] : zs;
  unsigned pw[4][4][2];
  #pragma unroll
  for (int m = 0; m < 4; m++) {
    short8 qa = (kg < 2) ? *(const short8*)&qh[(m*16 + row)*24 + kg*8] : zs;
    floatx4 sc[4];
    #pragma unroll
    for (int n = 0; n < 4; n++) sc[n] = MFMA16x32(qa, kb[n], zf);
    #pragma unroll
    for (int r = 0; r < 4; r++) {
      int t = m*16 + kg*4 + r;
      floatx4 abv = *(const floatx4*)&ab[t*64 + row*4];   // already ×log2e
      float e0 = exp2f(fmaf(sc[0][r], 0.25f*LOG2E, abv[0]));
      float e1 = exp2f(fmaf(sc[1][r], 0.25f*LOG2E, abv[1]));
      float e2 = exp2f(fmaf(sc[2][r], 0.25f*LOG2E, abv[2]));
      float e3 = exp2f(fmaf(sc[3][r], 0.25f*LOG2E, abv[3]));
      pw[m][r][0] = (unsigned)f2b(e0) | ((unsigned)f2b(e1) << 16);
      pw[m][r][1] = (unsigned)f2b(e2) | ((unsigned)f2b(e3) << 16);
    }
  }

  // ---- PV + row-sum (MFMA with ones) in two 32-col chunks ----
  floatx4 ov[4], ovs[4];
  #pragma unroll
  for (int m = 0; m < 4; m++) { ov[m] = zf; ovs[m] = zf; }
  #pragma unroll
  for (int ksk = 0; ksk < 2; ksk++) {
    asm volatile("" ::: "memory");
    #pragma unroll
    for (int m = 0; m < 4; m++)
      #pragma unroll
      for (int r = 0; r < 4; r++) {
        int t = m*16 + kg*4 + r;
        unsigned w = pw[m][r][ksk];
        pch[t*40 + row]      = (unsigned short)w;
        pch[t*40 + 16 + row] = (unsigned short)(w >> 16);
      }
    asm volatile("" ::: "memory");
    short8 vb = *(const short8*)&vt[(h*16 + row)*72 + ksk*32 + kg*8];
    #pragma unroll
    for (int m = 0; m < 4; m++) {
      short8 pa = *(const short8*)&pch[(m*16 + row)*40 + kg*8];
      ov[m]  = MFMA16x32(pa, vb, ov[m]);
      ovs[m] = MFMA16x32(pa, one8, ovs[m]);   // row sums (every col identical)
    }
  }
  __syncthreads();   // B1: all PV reads of vt/pchunk done; o64 may alias vt

  #pragma unroll
  for (int m = 0; m < 4; m++)
    #pragma unroll
    for (int r = 0; r < 4; r++) {
      float inv = __builtin_amdgcn_rcpf(ovs[m][r]);
      o64[(m*16 + kg*4 + r)*72 + h*16 + row] = f2b(ov[m][r] * inv);
    }
  __syncthreads();   // B2: o64 complete (cross-wave)

  // ---- phase 4: out projection; wave h owns t-rows h*16.. ----
  floatx4 op[6];
  #pragma unroll
  for (int n = 0; n < 6; n++) op[n] = zf;
  #pragma unroll
  for (int ks = 0; ks < 2; ks++) {
    short8 ao = *(const short8*)&o64[(h*16 + row)*72 + ks*32 + kg*8];
    #pragma unroll
    for (int n = 0; n < 6; n++) {
      short8 bo = *(const short8*)&outw[(n*16 + row)*64 + ks*32 + kg*8];
      op[n] = MFMA16x32(ao, bo, op[n]);
    }
  }

  // ---- phase 5: y = x + o; write y IN-PLACE over yx + into ybuf ----
  #pragma unroll
  for (int n = 0; n < 6; n++) {
    int o = n*16 + row;
    float ob = out_b[o];
    #pragma unroll
    for (int r = 0; r < 4; r++) {
      int t = h*16 + kg*4 + r;
      int gi = h0 + (t>>3), gj = w0 + (t&7);
      size_t gx = ((size_t)(gi*WWID + gj))*96 + o;
      float yv = op[n][r] + ob + b2f(xtw[gx]);   // read x THEN overwrite
      unsigned short yb = f2b(yv);
      xtw[gx] = yb;
      ybuf[t*104 + o] = yb;
    }
  }
  asm volatile("" ::: "memory");

  // ---- phase 6: FUSED conv1: h1 = leaky(w1 . y + b1); wave-local rows ----
  floatx4 ac1[6];
  #pragma unroll
  for (int n = 0; n < 6; n++) ac1[n] = zf;
  #pragma unroll
  for (int ks = 0; ks < 3; ks++) {
    int c0 = ks*32 + kg*8;
    short8 ay = *(const short8*)&ybuf[(h*16 + row)*104 + c0];
    #pragma unroll
    for (int n = 0; n < 6; n++) {
      short8 bw = *(const short8*)&w1b[(n*16 + row)*96 + c0];
      ac1[n] = MFMA16x32(ay, bw, ac1[n]);
    }
  }
  #pragma unroll
  for (int n = 0; n < 6; n++) {
    int o = n*16 + row;
    float bo = b1[o];
    #pragma unroll
    for (int r = 0; r < 4; r++) {
      int t = h*16 + kg*4 + r;
      int gi = h0 + (t>>3), gj = w0 + (t&7);
      float v = ac1[n][r] + bo;
      v = v >= 0.f ? v : 0.1f*v;
      h1w[((size_t)(gi*WWID + gj))*96 + o] = f2b(v);
    }
  }
}

// =====================================================================
// conv2 3x3 replicate-pad + leaky + residual. Implicit GEMM.
// WEIGHT-AMORTIZED n=8 (R10 theory, now WITHOUT the R11 spill confound):
// 8x32 px tile, 256 thr (4 waves: og 2 x pg 2), per s-step 3 weight loads
// feed 24 MFMAs (L2 weight traffic halved to 382MB). launch_bounds(256,2)
// -> VGPR cap 256 (need ~155, no spill). Pixel-major halo LDS [10x34][104]
// (70720B -> 2 blocks/CU), single-pass direct-scatter epilogue, setprio.
// grid 8*24*6 = 1152.
// =====================================================================
__global__ __launch_bounds__(256,2) void k_conv2(
    const unsigned short* __restrict__ h1, const unsigned short* __restrict__ y,
    const float* __restrict__ b2, const char* __restrict__ wsr,
    float* __restrict__ out) {
  __shared__ __align__(16) unsigned short h1t[340*104];   // 10x34 halo x 96ch (pad 104)
  const unsigned short* w2r = (const unsigned short*)(wsr + W2R_OFF);
  int blk = blockIdx.x;
  int b = blk / 144, rem = blk % 144;
  int i0 = (rem / 6) * 8, j0 = (rem % 6) * 32;
  int tid = threadIdx.x;

  // stage h1 tile with replicate-clamped halo
  for (int idx = tid; idx < 4080; idx += 256) {
    int pix = idx / 12, cc = (idx % 12) * 8;
    int hr = pix / 34, hc = pix % 34;
    int gi = min(max(i0 + hr - 1, 0), 191);
    int gj = min(max(j0 + hc - 1, 0), 191);
    *(short8*)&h1t[pix*104 + cc] =
        *(const short8*)&h1[((size_t)b*HW + (size_t)gi*WWID + gj)*96 + cc];
  }
  __syncthreads();

  int wv = tid >> 6, ln = tid & 63;
  int row = ln & 15, kg = ln >> 4;
  int og = wv >> 1, pg = wv & 1;

  const floatx4 zf = {0.f, 0.f, 0.f, 0.f};
  floatx4 acc[3][8];
  #pragma unroll
  for (int m = 0; m < 3; m++)
    #pragma unroll
    for (int n = 0; n < 8; n++) acc[m][n] = zf;

  for (int s = 0; s < 27; s++) {
    int tap = s / 3, c0 = (s % 3) * 32;
    int di = tap / 3, dj = tap % 3;
    short8 a[3], bb[8];
    #pragma unroll
    for (int m = 0; m < 3; m++)
      a[m] = *(const short8*)&w2r[(og*48 + m*16 + row)*864 + s*32 + kg*8];
    #pragma unroll
    for (int n = 0; n < 8; n++) {
      int p = pg*128 + n*16 + row;
      int pr = p >> 5, pc = p & 31;
      bb[n] = *(const short8*)&h1t[((pr + di)*34 + pc + dj)*104 + c0 + kg*8];
    }
    __builtin_amdgcn_s_setprio(1);
    #pragma unroll
    for (int m = 0; m < 3; m++)
      #pragma unroll
      for (int n = 0; n < 8; n++)
        acc[m][n] = MFMA16x32(a[m], bb[n], acc[m][n]);
    __builtin_amdgcn_s_setprio(0);
  }

  // epilogue: leaky(acc + b2) + y residual -> out NCHW fp32 (single pass)
  #pragma unroll
  for (int m = 0; m < 3; m++) {
    #pragma unroll
    for (int r = 0; r < 4; r++) {
      int o = og*48 + m*16 + kg*4 + r;
      float bo = b2[o];
      #pragma unroll
      for (int n = 0; n < 8; n++) {
        int p = pg*128 + n*16 + row;
        int pr = p >> 5, pc = p & 31;
        float hv = acc[m][n][r] + bo;
        hv = hv >= 0.f ? hv : 0.1f*hv;
        float yv = b2f(y[((size_t)b*HW + (size_t)(i0+pr)*WWID + j0+pc)*96 + o]);
        out[((size_t)(b*96 + o)*HH + i0 + pr)*WWID + j0 + pc] = yv + hv;
      }
    }
  }
}

// =====================================================================
extern "C" void kernel_launch(void* const* d_in, const int* in_sizes, int n_in,
                              void* d_out, int out_size, void* d_ws, size_t ws_size,
                              hipStream_t stream) {
  const float* x    = (const float*)d_in[0];
  const float* bias = (const float*)d_in[1];
  const float* bpw  = (const float*)d_in[2];
  const float* qkvw = (const float*)d_in[3];
  const float* qkvb = (const float*)d_in[4];
  const float* outw = (const float*)d_in[5];
  const float* outb = (const float*)d_in[6];
  const float* w1   = (const float*)d_in[7];
  const float* b1   = (const float*)d_in[8];
  const float* w2   = (const float*)d_in[9];
  const float* b2   = (const float*)d_in[10];

  char* ws = (char*)d_ws;
  float* out = (float*)d_out;
  unsigned short* yx = (unsigned short*)(ws + YX_OFF);
  unsigned short* h1 = (unsigned short*)(ws + H1_OFF);

  k_prep<<<128, 256, 0, stream>>>(bias, bpw, qkvw, outw, w1, w2, ws);
  k_xt  <<<4608, 256, 0, stream>>>(x, yx);
  k_attn<<<4608, 256, 0, stream>>>(yx, qkvb, outb, b1, ws, h1);
  k_conv2<<<1152, 256, 0, stream>>>(h1, yx, b2, ws, out);
}

// Round 25
// 224.850 us; speedup vs baseline: 1.0108x; 1.0108x over previous
//
#include <hip/hip_runtime.h>
#include <hip/hip_bf16.h>

typedef __attribute__((ext_vector_type(8))) short short8;
typedef __attribute__((ext_vector_type(4))) short short4v;
typedef __attribute__((ext_vector_type(4))) float floatx4;

#define MFMA16x32(a,b,c) __builtin_amdgcn_mfma_f32_16x16x32_bf16((a),(b),(c),0,0,0)

// exact round-to-nearest-even bf16 (no NaN path -- all values bounded here)
static __device__ __forceinline__ unsigned short f2b(float f) {
  unsigned u = __builtin_bit_cast(unsigned, f);
  return (unsigned short)((u + 0x7fffu + ((u >> 16) & 1u)) >> 16);
}
static __device__ __forceinline__ float b2f(unsigned short u) {
  unsigned v = ((unsigned)u) << 16;
  return __builtin_bit_cast(float, v);
}

#define HH 192
#define WWID 192
#define HW (192*192)

// ---- ws layout (bytes) ----
#define YX_OFF   0                      // x NHWC bf16 -> overwritten in-place with y
#define H1_OFF   56623104               // h1 NHWC bf16 (fused conv1 out of k_attn)
#define AB_OFF   113246208              // attn_bias f32 PERMUTED [t][row*4+n], ×log2e
#define QKVW_OFF 113262592              // qkv_w bf16 192*96
#define OUTW_OFF 113299456              // out_w bf16 96*64
#define W1_OFF   113311744              // conv1_w bf16 96*96
#define W2R_OFF  113330176              // conv2_w reordered bf16 96*864

#define LOG2E 1.44269504088896f

// =====================================================================
// prep: attn bias projection (permuted, pre-scaled by log2e) + repacks
// =====================================================================
__global__ __launch_bounds__(256) void k_prep(
    const float* __restrict__ bias, const float* __restrict__ bpw,
    const float* __restrict__ qkv_w, const float* __restrict__ out_w,
    const float* __restrict__ w1, const float* __restrict__ w2,
    char* __restrict__ ws) {
  int tid = blockIdx.x * blockDim.x + threadIdx.x;
  int nth = gridDim.x * blockDim.x;
  float* ab = (float*)(ws + AB_OFF);
  unsigned short* qkvw = (unsigned short*)(ws + QKVW_OFF);
  unsigned short* outw = (unsigned short*)(ws + OUTW_OFF);
  unsigned short* w1b  = (unsigned short*)(ws + W1_OFF);
  unsigned short* w2r  = (unsigned short*)(ws + W2R_OFF);

  for (int i = tid; i < 4096; i += nth) {
    float s = 0.f;
    #pragma unroll 8
    for (int k = 0; k < 64; k++) s += bias[k] * bpw[i*64 + k];
    int c = i & 63;                       // col = n*16 + row
    ab[(i & ~63) + ((c & 15) << 2) + (c >> 4)] = s * LOG2E;  // [t][row*4+n]
  }
  for (int i = tid; i < 192*96; i += nth) qkvw[i] = f2b(qkv_w[i]);
  for (int i = tid; i < 96*64;  i += nth) outw[i] = f2b(out_w[i]);
  for (int i = tid; i < 96*96;  i += nth) w1b[i]  = f2b(w1[i]);
  for (int i = tid; i < 96*864; i += nth) {
    int o = i / 864, k = i % 864;
    int tap = k / 96, c = k % 96;
    w2r[i] = f2b(w2[(o*96 + c)*9 + tap]);   // (O,C,3,3) -> [o][tap*96+c]
  }
}

// =====================================================================
// layout transform: x NCHW fp32 -> yx NHWC bf16, coalesced both sides
// =====================================================================
__global__ __launch_bounds__(256) void k_xt(
    const float* __restrict__ x, unsigned short* __restrict__ xt) {
  __shared__ __align__(16) float tile[96*65];
  int blk = blockIdx.x;
  int b = blk / 576, rem = blk % 576;
  int i = rem / 3, j0 = (rem % 3) * 64;
  int tid = threadIdx.x;
  const float* xb = x + (size_t)b*96*HW + (size_t)i*WWID + j0;

  for (int f = tid; f < 1536; f += 256) {
    int c = f >> 4, q = f & 15;
    *(floatx4*)&tile[c*65 + 4*q] = *(const floatx4*)&xb[(size_t)c*HW + 4*q];
  }
  __syncthreads();
  unsigned short* xtb = xt + ((size_t)b*HW + (size_t)i*WWID + j0) * 96;
  for (int f = tid; f < 768; f += 256) {
    int p = f / 12, c0 = (f % 12) * 8;
    short8 o;
    #pragma unroll
    for (int u = 0; u < 8; u++) o[u] = (short)f2b(tile[(c0+u)*65 + p]);
    *(short8*)&xtb[p*96 + c0] = o;
  }
}

// =====================================================================
// window attention + residual + FUSED conv1: 1 block per 8x8 window,
// 4 waves (wave = head). R14-best layout, no setprio (A/B confirmed).
// LDS 33792B -> 4 blocks/CU. 2 barriers. Scalar phase5/6 epilogues.
// =====================================================================
__global__ __launch_bounds__(256,4) void k_attn(
    unsigned short* yx, const float* __restrict__ qkv_b,
    const float* __restrict__ out_b, const float* __restrict__ b1,
    const char* __restrict__ wsr, unsigned short* __restrict__ h1) {
  __shared__ __align__(16) char smem[33792];
  unsigned short* vt   = (unsigned short*)smem;
  unsigned short* qkw  = (unsigned short*)(smem + 9216);
  unsigned short* o64  = (unsigned short*)smem;          // alias vt after B1
  unsigned short* ybuf = (unsigned short*)(smem + 9216); // [64][104] after PV (pch dead)

  const float* ab = (const float*)(wsr + AB_OFF);
  const unsigned short* qkvw = (const unsigned short*)(wsr + QKVW_OFF);
  const unsigned short* outw = (const unsigned short*)(wsr + OUTW_OFF);
  const unsigned short* w1b  = (const unsigned short*)(wsr + W1_OFF);

  int blk = blockIdx.x;
  int b = blk / 576, rem = blk % 576;
  int wi = rem / 24, wj = rem % 24;
  int h0 = wi * 8, w0 = wj * 8;
  unsigned short* xtw = yx + (size_t)b*HW*96;   // read x, write y in-place
  unsigned short* h1w = h1 + (size_t)b*HW*96;

  int tid = threadIdx.x;
  int h = tid >> 6, ln = tid & 63;
  int row = ln & 15, kg = ln >> 4;

  unsigned short* qh = qkw + h*3072;    // [64][24] u16
  unsigned short* kh = qh + 1536;       // [64][24] u16
  unsigned short* pch = qh;             // pchunk [64][40] aliases q+k (wave-local)

  const floatx4 zf = {0.f, 0.f, 0.f, 0.f};
  const short8 zs = {0,0,0,0,0,0,0,0};
  const short one_b = (short)0x3F80;    // bf16 1.0
  const short8 one8 = {one_b,one_b,one_b,one_b,one_b,one_b,one_b,one_b};

  // ---- phase 2: qkv GEMM, A straight from global yx; wave h owns head h ----
  floatx4 accq[4][3];
  #pragma unroll
  for (int m = 0; m < 4; m++)
    #pragma unroll
    for (int n = 0; n < 3; n++) accq[m][n] = zf;
  #pragma unroll
  for (int ks = 0; ks < 3; ks++) {
    int c0 = ks*32 + kg*8;
    short8 a[4], bb[3];
    #pragma unroll
    for (int m = 0; m < 4; m++) {
      int t = m*16 + row;
      a[m] = *(const short8*)&xtw[((size_t)((h0 + (t>>3))*WWID + w0 + (t&7)))*96 + c0];
    }
    #pragma unroll
    for (int n = 0; n < 3; n++)   // jt = n*4 + h  (q_h, k_h, v_h)
      bb[n] = *(const short8*)&qkvw[((n*4 + h)*16 + row)*96 + c0];
    #pragma unroll
    for (int m = 0; m < 4; m++)
      #pragma unroll
      for (int n = 0; n < 3; n++) accq[m][n] = MFMA16x32(a[m], bb[n], accq[m][n]);
  }
  float qb0 = qkv_b[h*16 + row], qb1 = qkv_b[64 + h*16 + row], qb2 = qkv_b[128 + h*16 + row];
  #pragma unroll
  for (int m = 0; m < 4; m++) {
    #pragma unroll
    for (int r = 0; r < 4; r++) {
      int t = m*16 + kg*4 + r;
      qh[t*24 + row] = f2b(accq[m][0][r] + qb0);
      kh[t*24 + row] = f2b(accq[m][1][r] + qb1);
    }
    short4v vv;
    #pragma unroll
    for (int r = 0; r < 4; r++) vv[r] = (short)f2b(accq[m][2][r] + qb2);
    *(short4v*)&vt[(h*16 + row)*72 + m*16 + kg*4] = vv;   // vt[d][t] packed b64
  }
  asm volatile("" ::: "memory");

  // ---- phase 3: scores (K=16 zero-padded) + exp (no max; denom via MFMA) ----
  short8 kb[4];
  #pragma unroll
  for (int n = 0; n < 4; n++)
    kb[n] = (kg < 2) ? *(const short8*)&kh[(n*16 + row)*24 + kg*8] : zs;
  unsigned pw[4][4][2];
  #pragma unroll
  for (int m = 0; m < 4; m++) {
    short8 qa = (kg < 2) ? *(const short8*)&qh[(m*16 + row)*24 + kg*8] : zs;
    floatx4 sc[4];
    #pragma unroll
    for (int n = 0; n < 4; n++) sc[n] = MFMA16x32(qa, kb[n], zf);
    #pragma unroll
    for (int r = 0; r < 4; r++) {
      int t = m*16 + kg*4 + r;
      floatx4 abv = *(const floatx4*)&ab[t*64 + row*4];   // already ×log2e
      float e0 = exp2f(fmaf(sc[0][r], 0.25f*LOG2E, abv[0]));
      float e1 = exp2f(fmaf(sc[1][r], 0.25f*LOG2E, abv[1]));
      float e2 = exp2f(fmaf(sc[2][r], 0.25f*LOG2E, abv[2]));
      float e3 = exp2f(fmaf(sc[3][r], 0.25f*LOG2E, abv[3]));
      pw[m][r][0] = (unsigned)f2b(e0) | ((unsigned)f2b(e1) << 16);
      pw[m][r][1] = (unsigned)f2b(e2) | ((unsigned)f2b(e3) << 16);
    }
  }

  // ---- PV + row-sum (MFMA with ones) in two 32-col chunks ----
  floatx4 ov[4], ovs[4];
  #pragma unroll
  for (int m = 0; m < 4; m++) { ov[m] = zf; ovs[m] = zf; }
  #pragma unroll
  for (int ksk = 0; ksk < 2; ksk++) {
    asm volatile("" ::: "memory");
    #pragma unroll
    for (int m = 0; m < 4; m++)
      #pragma unroll
      for (int r = 0; r < 4; r++) {
        int t = m*16 + kg*4 + r;
        unsigned w = pw[m][r][ksk];
        pch[t*40 + row]      = (unsigned short)w;
        pch[t*40 + 16 + row] = (unsigned short)(w >> 16);
      }
    asm volatile("" ::: "memory");
    short8 vb = *(const short8*)&vt[(h*16 + row)*72 + ksk*32 + kg*8];
    #pragma unroll
    for (int m = 0; m < 4; m++) {
      short8 pa = *(const short8*)&pch[(m*16 + row)*40 + kg*8];
      ov[m]  = MFMA16x32(pa, vb, ov[m]);
      ovs[m] = MFMA16x32(pa, one8, ovs[m]);   // row sums (every col identical)
    }
  }
  __syncthreads();   // B1: all PV reads of vt/pchunk done; o64 may alias vt

  #pragma unroll
  for (int m = 0; m < 4; m++)
    #pragma unroll
    for (int r = 0; r < 4; r++) {
      float inv = __builtin_amdgcn_rcpf(ovs[m][r]);
      o64[(m*16 + kg*4 + r)*72 + h*16 + row] = f2b(ov[m][r] * inv);
    }
  __syncthreads();   // B2: o64 complete (cross-wave)

  // ---- phase 4: out projection; wave h owns t-rows h*16.. ----
  floatx4 op[6];
  #pragma unroll
  for (int n = 0; n < 6; n++) op[n] = zf;
  #pragma unroll
  for (int ks = 0; ks < 2; ks++) {
    short8 ao = *(const short8*)&o64[(h*16 + row)*72 + ks*32 + kg*8];
    #pragma unroll
    for (int n = 0; n < 6; n++) {
      short8 bo = *(const short8*)&outw[(n*16 + row)*64 + ks*32 + kg*8];
      op[n] = MFMA16x32(ao, bo, op[n]);
    }
  }

  // ---- phase 5: y = x + o; write y IN-PLACE over yx + into ybuf ----
  #pragma unroll
  for (int n = 0; n < 6; n++) {
    int o = n*16 + row;
    float ob = out_b[o];
    #pragma unroll
    for (int r = 0; r < 4; r++) {
      int t = h*16 + kg*4 + r;
      int gi = h0 + (t>>3), gj = w0 + (t&7);
      size_t gx = ((size_t)(gi*WWID + gj))*96 + o;
      float yv = op[n][r] + ob + b2f(xtw[gx]);   // read x THEN overwrite
      unsigned short yb = f2b(yv);
      xtw[gx] = yb;
      ybuf[t*104 + o] = yb;
    }
  }
  asm volatile("" ::: "memory");

  // ---- phase 6: FUSED conv1: h1 = leaky(w1 . y + b1); wave-local rows ----
  floatx4 ac1[6];
  #pragma unroll
  for (int n = 0; n < 6; n++) ac1[n] = zf;
  #pragma unroll
  for (int ks = 0; ks < 3; ks++) {
    int c0 = ks*32 + kg*8;
    short8 ay = *(const short8*)&ybuf[(h*16 + row)*104 + c0];
    #pragma unroll
    for (int n = 0; n < 6; n++) {
      short8 bw = *(const short8*)&w1b[(n*16 + row)*96 + c0];
      ac1[n] = MFMA16x32(ay, bw, ac1[n]);
    }
  }
  #pragma unroll
  for (int n = 0; n < 6; n++) {
    int o = n*16 + row;
    float bo = b1[o];
    #pragma unroll
    for (int r = 0; r < 4; r++) {
      int t = h*16 + kg*4 + r;
      int gi = h0 + (t>>3), gj = w0 + (t&7);
      float v = ac1[n][r] + bo;
      v = v >= 0.f ? v : 0.1f*v;
      h1w[((size_t)(gi*WWID + gj))*96 + o] = f2b(v);
    }
  }
}

// =====================================================================
// conv2 3x3 replicate-pad + leaky + residual. Implicit GEMM.
// R23-best: R5-exact structure + s_setprio on MFMA cluster (+16% A/B).
// 8x32 px tile, 512 thr (8 waves: og 2 x pg 4, n=4), pixel-major halo
// LDS [10x34][104], single-pass direct-scatter epilogue. grid 1152.
// =====================================================================
__global__ __launch_bounds__(512,4) void k_conv2(
    const unsigned short* __restrict__ h1, const unsigned short* __restrict__ y,
    const float* __restrict__ b2, const char* __restrict__ wsr,
    float* __restrict__ out) {
  __shared__ __align__(16) unsigned short h1t[340*104];   // 10x34 halo x 96ch (pad 104)
  const unsigned short* w2r = (const unsigned short*)(wsr + W2R_OFF);
  int blk = blockIdx.x;
  int b = blk / 144, rem = blk % 144;
  int i0 = (rem / 6) * 8, j0 = (rem % 6) * 32;
  int tid = threadIdx.x;

  // stage h1 tile with replicate-clamped halo
  for (int idx = tid; idx < 4080; idx += 512) {
    int pix = idx / 12, cc = (idx % 12) * 8;
    int hr = pix / 34, hc = pix % 34;
    int gi = min(max(i0 + hr - 1, 0), 191);
    int gj = min(max(j0 + hc - 1, 0), 191);
    *(short8*)&h1t[pix*104 + cc] =
        *(const short8*)&h1[((size_t)b*HW + (size_t)gi*WWID + gj)*96 + cc];
  }
  __syncthreads();

  int wv = tid >> 6, ln = tid & 63;
  int row = ln & 15, kg = ln >> 4;
  int og = wv >> 2, pg = wv & 3;

  const floatx4 zf = {0.f, 0.f, 0.f, 0.f};
  floatx4 acc[3][4];
  #pragma unroll
  for (int m = 0; m < 3; m++)
    #pragma unroll
    for (int n = 0; n < 4; n++) acc[m][n] = zf;

  for (int s = 0; s < 27; s++) {
    int tap = s / 3, c0 = (s % 3) * 32;
    int di = tap / 3, dj = tap % 3;
    short8 a[3], bb[4];
    #pragma unroll
    for (int m = 0; m < 3; m++)
      a[m] = *(const short8*)&w2r[(og*48 + m*16 + row)*864 + s*32 + kg*8];
    #pragma unroll
    for (int n = 0; n < 4; n++) {
      int p = pg*64 + n*16 + row;
      int pr = p >> 5, pc = p & 31;
      bb[n] = *(const short8*)&h1t[((pr + di)*34 + pc + dj)*104 + c0 + kg*8];
    }
    __builtin_amdgcn_s_setprio(1);
    #pragma unroll
    for (int m = 0; m < 3; m++)
      #pragma unroll
      for (int n = 0; n < 4; n++)
        acc[m][n] = MFMA16x32(a[m], bb[n], acc[m][n]);
    __builtin_amdgcn_s_setprio(0);
  }

  // epilogue: leaky(acc + b2) + y residual -> out NCHW fp32 (single pass)
  #pragma unroll
  for (int m = 0; m < 3; m++) {
    #pragma unroll
    for (int r = 0; r < 4; r++) {
      int o = og*48 + m*16 + kg*4 + r;
      float bo = b2[o];
      #pragma unroll
      for (int n = 0; n < 4; n++) {
        int p = pg*64 + n*16 + row;
        int pr = p >> 5, pc = p & 31;
        float hv = acc[m][n][r] + bo;
        hv = hv >= 0.f ? hv : 0.1f*hv;
        float yv = b2f(y[((size_t)b*HW + (size_t)(i0+pr)*WWID + j0+pc)*96 + o]);
        out[((size_t)(b*96 + o)*HH + i0 + pr)*WWID + j0 + pc] = yv + hv;
      }
    }
  }
}

// =====================================================================
extern "C" void kernel_launch(void* const* d_in, const int* in_sizes, int n_in,
                              void* d_out, int out_size, void* d_ws, size_t ws_size,
                              hipStream_t stream) {
  const float* x    = (const float*)d_in[0];
  const float* bias = (const float*)d_in[1];
  const float* bpw  = (const float*)d_in[2];
  const float* qkvw = (const float*)d_in[3];
  const float* qkvb = (const float*)d_in[4];
  const float* outw = (const float*)d_in[5];
  const float* outb = (const float*)d_in[6];
  const float* w1   = (const float*)d_in[7];
  const float* b1   = (const float*)d_in[8];
  const float* w2   = (const float*)d_in[9];
  const float* b2   = (const float*)d_in[10];

  char* ws = (char*)d_ws;
  float* out = (float*)d_out;
  unsigned short* yx = (unsigned short*)(ws + YX_OFF);
  unsigned short* h1 = (unsigned short*)(ws + H1_OFF);

  k_prep<<<128, 256, 0, stream>>>(bias, bpw, qkvw, outw, w1, w2, ws);
  k_xt  <<<4608, 256, 0, stream>>>(x, yx);
  k_attn<<<4608, 256, 0, stream>>>(yx, qkvb, outb, b1, ws, h1);
  k_conv2<<<1152, 512, 0, stream>>>(h1, yx, b2, ws, out);
}